// Round 1
// baseline (12048.103 us; speedup 1.0000x reference)
//
#include <hip/hip_runtime.h>

// Decoder (DA-RNN style): B=512, T=128, E=256, D=256, OUT=1
// Strategy: 128-step scan, 3 kernels/step on one stream (graph-friendly),
// h/c double-buffered by parity. All fp32 this round (correctness first).

#define BB 512
#define TT 128
#define EE 256
#define DD 256
#define NBC 8

__device__ __forceinline__ float fast_tanh(float x) {
    // tanh(x) = 1 - 2/(exp(2x)+1); overflow-safe (exp->inf => 1, exp->0 => -1)
    return 1.0f - 2.0f / (__expf(2.0f * x) + 1.0f);
}
__device__ __forceinline__ float fast_sig(float x) {
    return 1.0f / (1.0f + __expf(-x));
}

// one-time: WhhT[k][j] = Whh[j][k]; bias[j] = bih[j]+bhh[j]
__global__ __launch_bounds__(256) void k_prep(const float* __restrict__ Whh,
                                              const float* __restrict__ bih,
                                              const float* __restrict__ bhh,
                                              float* __restrict__ WhhT,
                                              float* __restrict__ bias) {
    int k = blockIdx.x;            // 0..255
    int tid = threadIdx.x;
    for (int j = tid; j < 1024; j += 256)
        WhhT[k * 1024 + j] = Whh[j * 256 + k];
    if (blockIdx.x < 4) {
        int j = blockIdx.x * 256 + tid;
        bias[j] = bih[j] + bhh[j];
    }
}

// one-time: enc_proj[n][f] = sum_e ie[n][e] * aW1[512+e][f], n in [0,B*T)
__global__ __launch_bounds__(256) void k_encproj(const float* __restrict__ ie,
                                                 const float* __restrict__ aW1,
                                                 float* __restrict__ ep) {
    __shared__ float a[32][EE];
    int row0 = blockIdx.x * 32;
    int tid = threadIdx.x;
    for (int r = 0; r < 32; ++r)
        a[r][tid] = ie[(size_t)(row0 + r) * EE + tid];
    __syncthreads();
    float acc[32];
    #pragma unroll
    for (int r = 0; r < 32; ++r) acc[r] = 0.f;
    const float* wenc = aW1 + 512 * EE;      // encoder rows of aW1
    for (int e = 0; e < EE; e += 4) {
        float w0 = wenc[(e + 0) * EE + tid];
        float w1 = wenc[(e + 1) * EE + tid];
        float w2 = wenc[(e + 2) * EE + tid];
        float w3 = wenc[(e + 3) * EE + tid];
        #pragma unroll
        for (int r = 0; r < 32; ++r) {
            float4 av = *(const float4*)&a[r][e];
            acc[r] += av.x * w0 + av.y * w1 + av.z * w2 + av.w * w3;
        }
    }
    for (int r = 0; r < 32; ++r)
        ep[(size_t)(row0 + r) * EE + tid] = acc[r];
}

// per-step: q[b][f] = sum_{k<512} [h;c][b][k] * aW1[k][f]
__global__ __launch_bounds__(256) void k_q(const float* __restrict__ h,
                                           const float* __restrict__ c,
                                           const float* __restrict__ aW1,
                                           float* __restrict__ q) {
    __shared__ float hc[4][512];
    int b0 = blockIdx.x * 4;
    int tid = threadIdx.x;
    #pragma unroll
    for (int r = 0; r < 4; ++r) {
        hc[r][tid] = h[(b0 + r) * DD + tid];
        hc[r][256 + tid] = c[(b0 + r) * DD + tid];
    }
    __syncthreads();
    float acc[4] = {0.f, 0.f, 0.f, 0.f};
    for (int k = 0; k < 512; k += 4) {
        float w0 = aW1[(k + 0) * EE + tid];
        float w1 = aW1[(k + 1) * EE + tid];
        float w2 = aW1[(k + 2) * EE + tid];
        float w3 = aW1[(k + 3) * EE + tid];
        #pragma unroll
        for (int r = 0; r < 4; ++r) {
            float4 hv = *(const float4*)&hc[r][k];
            acc[r] += hv.x * w0 + hv.y * w1 + hv.z * w2 + hv.w * w3;
        }
    }
    #pragma unroll
    for (int r = 0; r < 4; ++r)
        q[(b0 + r) * EE + tid] = acc[r];
}

// per-step: one block per b. scores -> softmax -> ctx -> y_tilde
__global__ __launch_bounds__(256) void k_attn(const float* __restrict__ ep,
                                              const float* __restrict__ ie,
                                              const float* __restrict__ q,
                                              const float* __restrict__ ab1,
                                              const float* __restrict__ aW2,
                                              const float* __restrict__ fcW,
                                              const float* __restrict__ fcb,
                                              const float* __restrict__ yh,
                                              float* __restrict__ ctx,
                                              float* __restrict__ yt,
                                              int t) {
    __shared__ float s_sc[TT];
    __shared__ float s_ctx[4][EE];
    int b = blockIdx.x;
    int tid = threadIdx.x;
    int wave = tid >> 6, lane = tid & 63;
    int f0 = lane * 4;

    float4 qb = *(const float4*)&q[b * EE + f0];
    float4 b1 = *(const float4*)&ab1[f0];
    qb.x += b1.x; qb.y += b1.y; qb.z += b1.z; qb.w += b1.w;
    float4 w2 = *(const float4*)&aW2[f0];

    // scores (ab2 is an additive constant -> softmax-invariant, skipped)
    const float* epb = ep + (size_t)b * TT * EE;
    for (int tt = wave; tt < TT; tt += 4) {
        float4 x = *(const float4*)&epb[tt * EE + f0];
        float s = fast_tanh(qb.x + x.x) * w2.x
                + fast_tanh(qb.y + x.y) * w2.y
                + fast_tanh(qb.z + x.z) * w2.z
                + fast_tanh(qb.w + x.w) * w2.w;
        #pragma unroll
        for (int off = 32; off; off >>= 1) s += __shfl_xor(s, off);
        if (lane == 0) s_sc[tt] = s;
    }
    __syncthreads();

    // softmax over 128 scores (wave 0)
    if (wave == 0) {
        float v0 = s_sc[lane], v1 = s_sc[lane + 64];
        float m = fmaxf(v0, v1);
        #pragma unroll
        for (int off = 32; off; off >>= 1) m = fmaxf(m, __shfl_xor(m, off));
        float e0 = __expf(v0 - m), e1 = __expf(v1 - m);
        float s = e0 + e1;
        #pragma unroll
        for (int off = 32; off; off >>= 1) s += __shfl_xor(s, off);
        float inv = 1.0f / s;
        s_sc[lane] = e0 * inv;
        s_sc[lane + 64] = e1 * inv;
    }
    __syncthreads();

    // ctx[b][e] = sum_t attn[t] * ie[b][t][e]
    const float* ieb = ie + (size_t)b * TT * EE;
    float4 acc = {0.f, 0.f, 0.f, 0.f};
    for (int tt = wave; tt < TT; tt += 4) {
        float a = s_sc[tt];
        float4 x = *(const float4*)&ieb[tt * EE + f0];
        acc.x += a * x.x; acc.y += a * x.y; acc.z += a * x.z; acc.w += a * x.w;
    }
    *(float4*)&s_ctx[wave][f0] = acc;
    __syncthreads();
    if (wave == 0) {
        float4 r0 = *(const float4*)&s_ctx[0][f0];
        float4 r1 = *(const float4*)&s_ctx[1][f0];
        float4 r2 = *(const float4*)&s_ctx[2][f0];
        float4 r3 = *(const float4*)&s_ctx[3][f0];
        float4 r;
        r.x = r0.x + r1.x + r2.x + r3.x;
        r.y = r0.y + r1.y + r2.y + r3.y;
        r.z = r0.z + r1.z + r2.z + r3.z;
        r.w = r0.w + r1.w + r2.w + r3.w;
        *(float4*)&ctx[b * EE + f0] = r;
        // y_tilde[b] = dot(ctx, fcW[:256]) + y_t * fcW[256] + fcb
        float4 fw = *(const float4*)&fcW[f0];
        float p = r.x * fw.x + r.y * fw.y + r.z * fw.z + r.w * fw.w;
        #pragma unroll
        for (int off = 32; off; off >>= 1) p += __shfl_xor(p, off);
        if (lane == 0)
            yt[b] = p + yh[b * TT + t] * fcW[256] + fcb[0];
    }
}

// per-step: gates = y_tilde*Wih + h@Whh.T + bias ; LSTM update
// grid (B/NBC, 4): block owns NBC b-rows x 64 d-cols; wave w = gate type w.
__global__ __launch_bounds__(256) void k_lstm(const float* __restrict__ h_in,
                                              const float* __restrict__ c_in,
                                              const float* __restrict__ WhhT,
                                              const float* __restrict__ Wih,
                                              const float* __restrict__ bias,
                                              const float* __restrict__ yt,
                                              float* __restrict__ h_out,
                                              float* __restrict__ c_out) {
    __shared__ float s_h[NBC][DD];
    __shared__ float s_g[4][NBC][64];
    int b0 = blockIdx.x * NBC;
    int db = blockIdx.y;           // 0..3
    int tid = threadIdx.x;
    int wave = tid >> 6, lane = tid & 63;
    int j = wave * 256 + db * 64 + lane;   // gate row in [0,1024)

    for (int idx = tid; idx < NBC * DD; idx += 256)
        s_h[idx >> 8][idx & 255] = h_in[(b0 + (idx >> 8)) * DD + (idx & 255)];
    __syncthreads();

    float acc[NBC];
    #pragma unroll
    for (int r = 0; r < NBC; ++r) acc[r] = 0.f;
    for (int k = 0; k < DD; k += 4) {
        float w0 = WhhT[(k + 0) * 1024 + j];
        float w1 = WhhT[(k + 1) * 1024 + j];
        float w2 = WhhT[(k + 2) * 1024 + j];
        float w3 = WhhT[(k + 3) * 1024 + j];
        #pragma unroll
        for (int r = 0; r < NBC; ++r) {
            float4 hv = *(const float4*)&s_h[r][k];
            acc[r] += hv.x * w0 + hv.y * w1 + hv.z * w2 + hv.w * w3;
        }
    }
    float wih = Wih[j];
    float bs = bias[j];
    #pragma unroll
    for (int r = 0; r < NBC; ++r)
        s_g[wave][r][lane] = acc[r] + yt[b0 + r] * wih + bs;
    __syncthreads();

    for (int idx = tid; idx < NBC * 64; idx += 256) {
        int r = idx >> 6, dl = idx & 63;
        int gidx = (b0 + r) * DD + db * 64 + dl;
        float gi = s_g[0][r][dl], gf = s_g[1][r][dl],
              gg = s_g[2][r][dl], go = s_g[3][r][dl];
        float cv = c_in[gidx];
        float c2 = fast_sig(gf) * cv + fast_sig(gi) * fast_tanh(gg);
        c_out[gidx] = c2;
        h_out[gidx] = fast_sig(go) * fast_tanh(c2);
    }
}

// final: out[b] = dot(h,ffW[:256]) + dot(ctx,ffW[256:]) + ffb
__global__ __launch_bounds__(256) void k_final(const float* __restrict__ h,
                                               const float* __restrict__ ctx,
                                               const float* __restrict__ ffW,
                                               const float* __restrict__ ffb,
                                               float* __restrict__ out) {
    __shared__ float s_p[4];
    int b = blockIdx.x, tid = threadIdx.x;
    int wave = tid >> 6, lane = tid & 63;
    float p = h[b * DD + tid] * ffW[tid] + ctx[b * EE + tid] * ffW[256 + tid];
    #pragma unroll
    for (int off = 32; off; off >>= 1) p += __shfl_xor(p, off);
    if (lane == 0) s_p[wave] = p;
    __syncthreads();
    if (tid == 0) out[b] = s_p[0] + s_p[1] + s_p[2] + s_p[3] + ffb[0];
}

extern "C" void kernel_launch(void* const* d_in, const int* in_sizes, int n_in,
                              void* d_out, int out_size, void* d_ws, size_t ws_size,
                              hipStream_t stream) {
    const float* ie  = (const float*)d_in[0];   // [B,T,E]
    const float* yh  = (const float*)d_in[1];   // [B,T,1]
    const float* aW1 = (const float*)d_in[2];   // [768,256]
    const float* ab1 = (const float*)d_in[3];   // [256]
    const float* aW2 = (const float*)d_in[4];   // [256,1]
    // d_in[5] = ab2: additive const inside softmax -> invariant, unused
    const float* Wih = (const float*)d_in[6];   // [1024,1]
    const float* Whh = (const float*)d_in[7];   // [1024,256]
    const float* bih = (const float*)d_in[8];   // [1024]
    const float* bhh = (const float*)d_in[9];   // [1024]
    const float* fcW = (const float*)d_in[10];  // [1,257]
    const float* fcb = (const float*)d_in[11];  // [1]
    const float* ffW = (const float*)d_in[12];  // [1,512]
    const float* ffb = (const float*)d_in[13];  // [1]
    float* out = (float*)d_out;
    float* ws  = (float*)d_ws;

    // workspace layout (floats)
    float* ep   = ws;                            // B*T*E = 16,777,216
    float* q    = ep + (size_t)BB * TT * EE;     // B*E
    float* ctx  = q + BB * EE;                   // B*E
    float* yt   = ctx + BB * EE;                 // B
    float* hbuf = yt + BB;                       // 2*B*D
    float* cbuf = hbuf + 2 * BB * DD;            // 2*B*D
    float* WhhT = cbuf + 2 * BB * DD;            // 256*1024
    float* bias = WhhT + DD * 1024;              // 1024

    // zero h/c (both parities) — poisoned workspace otherwise
    hipMemsetAsync(hbuf, 0, (size_t)4 * BB * DD * sizeof(float), stream);

    k_prep<<<256, 256, 0, stream>>>(Whh, bih, bhh, WhhT, bias);
    k_encproj<<<2048, 256, 0, stream>>>(ie, aW1, ep);

    for (int t = 0; t < TT; ++t) {
        int p = t & 1;
        const float* hi = hbuf + (size_t)p * BB * DD;
        const float* ci = cbuf + (size_t)p * BB * DD;
        float* ho = hbuf + (size_t)(1 - p) * BB * DD;
        float* co = cbuf + (size_t)(1 - p) * BB * DD;
        k_q<<<128, 256, 0, stream>>>(hi, ci, aW1, q);
        k_attn<<<512, 256, 0, stream>>>(ep, ie, q, ab1, aW2, fcW, fcb, yh, ctx, yt, t);
        k_lstm<<<dim3(64, 4), 256, 0, stream>>>(hi, ci, WhhT, Wih, bias, yt, ho, co);
    }
    // after 128 steps, live parity is 0
    k_final<<<512, 256, 0, stream>>>(hbuf, ctx, ffW, ffb, out);
}

// Round 2
// 6643.423 us; speedup vs baseline: 1.8135x; 1.8135x over previous
//
#include <hip/hip_runtime.h>

// DA-RNN decoder: B=512, T=128, E=256, D=256, OUT=1.
// Key insight: every per-step phase is batch-row-local (q, softmax, ctx,
// y_tilde, gates, LSTM update for row b depend only on row-b state + shared
// weights). So the whole 128-step scan runs in ONE persistent kernel:
// 256 blocks x 512 threads, NB=2 batch rows per block, h/c live in LDS.
// Weights (aW1 decoder part, Whh) pre-packed to bf16 in load-order; ep
// (encoder projection) precomputed in bf16; ie streamed fp32 for ctx accuracy.

#define BB 512
#define TT 128
#define EE 256
#define DD 256
#define NB 2
#define NTHR 512

__device__ __forceinline__ float bflo(unsigned int u) {
    union { unsigned int i; float f; } v; v.i = u << 16; return v.f;
}
__device__ __forceinline__ float bfhi(unsigned int u) {
    union { unsigned int i; float f; } v; v.i = u & 0xFFFF0000u; return v.f;
}
__device__ __forceinline__ unsigned short f2bf(float x) {
    union { float f; unsigned int i; } v; v.f = x;
    unsigned int r = (v.i + 0x7FFFu + ((v.i >> 16) & 1u)) >> 16;
    return (unsigned short)r;
}
__device__ __forceinline__ float ftanh(float x) {
    return 1.f - 2.f * __builtin_amdgcn_rcpf(__expf(2.f * x) + 1.f);
}
__device__ __forceinline__ float fsig(float x) {
    return __builtin_amdgcn_rcpf(1.f + __expf(-x));
}
__device__ __forceinline__ float dot8(uint4 w, float4 a, float4 b) {
    return bflo(w.x) * a.x + bfhi(w.x) * a.y + bflo(w.y) * a.z + bfhi(w.y) * a.w
         + bflo(w.z) * b.x + bfhi(w.z) * b.y + bflo(w.w) * b.z + bfhi(w.w) * b.w;
}

// Pack weights to bf16 in the exact load order of the main kernel.
// aW1q[(g*256+f)*8+j] = aW1[g*8+j][f]      (g<64 -> k=g*8+j < 512)
// WhhP[(i*1024+jj)*8+j] = Whh[jj][i*8+j]   (i<32)
// bias = bih + bhh
__global__ __launch_bounds__(256) void k_pack(const float* __restrict__ aW1,
                                              const float* __restrict__ Whh,
                                              const float* __restrict__ bih,
                                              const float* __restrict__ bhh,
                                              unsigned short* __restrict__ aW1q,
                                              unsigned short* __restrict__ WhhP,
                                              float* __restrict__ bias) {
    int bid = blockIdx.x, tid = threadIdx.x;
    if (bid < 512) {
        int o = bid * 256 + tid;                 // < 131072
        int g = o >> 11, f = (o >> 3) & 255, j = o & 7;
        aW1q[o] = f2bf(aW1[(g * 8 + j) * EE + f]);
    } else if (bid < 1536) {
        int o = (bid - 512) * 256 + tid;         // < 262144
        int i = o >> 13, jj = (o >> 3) & 1023, j = o & 7;
        WhhP[o] = f2bf(Whh[jj * DD + i * 8 + j]);
    } else {
        int j = (bid - 1536) * 256 + tid;        // < 1024
        bias[j] = bih[j] + bhh[j];
    }
}

// enc_proj[n][f] = sum_e ie[n][e]*aW1[512+e][f]; fp32 accum, bf16 store.
__global__ __launch_bounds__(256) void k_encproj(const float* __restrict__ ie,
                                                 const float* __restrict__ aW1,
                                                 unsigned short* __restrict__ ep) {
    __shared__ float a[32][EE];
    int row0 = blockIdx.x * 32;
    int tid = threadIdx.x;
    for (int r = 0; r < 32; ++r)
        a[r][tid] = ie[(size_t)(row0 + r) * EE + tid];
    __syncthreads();
    float acc[32];
    #pragma unroll
    for (int r = 0; r < 32; ++r) acc[r] = 0.f;
    const float* wenc = aW1 + 512 * EE;
    for (int e = 0; e < EE; e += 4) {
        float w0 = wenc[(e + 0) * EE + tid];
        float w1 = wenc[(e + 1) * EE + tid];
        float w2 = wenc[(e + 2) * EE + tid];
        float w3 = wenc[(e + 3) * EE + tid];
        #pragma unroll
        for (int r = 0; r < 32; ++r) {
            float4 av = *(const float4*)&a[r][e];
            acc[r] += av.x * w0 + av.y * w1 + av.z * w2 + av.w * w3;
        }
    }
    for (int r = 0; r < 32; ++r)
        ep[(size_t)(row0 + r) * EE + tid] = f2bf(acc[r]);
}

__global__ __launch_bounds__(NTHR) void k_main(
    const unsigned short* __restrict__ ep, const float* __restrict__ ie,
    const float* __restrict__ yh,
    const unsigned short* __restrict__ aW1q, const unsigned short* __restrict__ WhhP,
    const float* __restrict__ bias_, const float* __restrict__ ab1,
    const float* __restrict__ aW2, const float* __restrict__ Wih,
    const float* __restrict__ fcW, const float* __restrict__ fcb,
    const float* __restrict__ ffW, const float* __restrict__ ffb,
    float* __restrict__ out) {
    __shared__ float s_h[NB][DD];
    __shared__ float s_c[NB][DD];
    __shared__ float s_q[NB][EE];
    __shared__ float s_qp[2][NB][EE];
    __shared__ float s_sc[NB * TT];
    __shared__ float s_cp[8][NB][EE];
    __shared__ float s_ctx[NB][EE];
    __shared__ float s_g[NB][4 * DD];
    __shared__ float s_wih[4 * DD];
    __shared__ float s_bias[4 * DD];
    __shared__ float s_ab1[EE];
    __shared__ float s_fcw[EE + 1];
    __shared__ float s_yt[NB];

    const int tid = threadIdx.x;
    const int wave = tid >> 6, lane = tid & 63;
    const int b0 = blockIdx.x * NB;

    for (int i = tid; i < 4 * DD; i += NTHR) { s_wih[i] = Wih[i]; s_bias[i] = bias_[i]; }
    for (int i = tid; i < EE; i += NTHR) s_ab1[i] = ab1[i];
    if (tid < EE + 1) s_fcw[tid] = fcW[tid];
    for (int i = tid; i < NB * DD; i += NTHR) { (&s_h[0][0])[i] = 0.f; (&s_c[0][0])[i] = 0.f; }

    // lane-constant setup for scores/ctx phases
    const int e0 = (lane & 31) * 8;
    float tw2[8]; float sw2 = 0.f;
    #pragma unroll
    for (int j = 0; j < 8; ++j) { float w = aW2[e0 + j]; tw2[j] = 2.f * w; sw2 += w; }

    const int qf = tid & 255, qh = tid >> 8;          // q-phase: f-column, k-half
    const float* hcsrc = qh ? &s_c[0][0] : &s_h[0][0];
    const unsigned short* qWbase = aW1q + ((size_t)(qh * 32) * 256 + qf) * 8;
    const unsigned short* wP0 = WhhP + (size_t)tid * 8;
    const unsigned short* wP1 = WhhP + (size_t)(tid + 512) * 8;
    const int rrow = wave * 2 + (lane >> 5);          // row offset within 16-row group
    const float fcb0 = fcb[0];
    const unsigned short* epb0 = ep + (size_t)(b0 + 0) * TT * EE + e0;
    const unsigned short* epb1 = ep + (size_t)(b0 + 1) * TT * EE + e0;
    const float* ieb0 = ie + (size_t)(b0 + 0) * TT * EE + e0;
    const float* ieb1 = ie + (size_t)(b0 + 1) * TT * EE + e0;

    __syncthreads();

    for (int t = 0; t < TT; ++t) {
        // ---------- q = [h;c] @ aW1[:512]  (each thread: one f, one k-half) ----------
        float qa0 = 0.f, qa1 = 0.f;
        #pragma unroll 4
        for (int i = 0; i < 32; ++i) {
            uint4 wv = *(const uint4*)(qWbase + i * 2048);
            int kk = i * 8;
            float4 ha = *(const float4*)(hcsrc + 0 * DD + kk);
            float4 hb = *(const float4*)(hcsrc + 0 * DD + kk + 4);
            float4 hc = *(const float4*)(hcsrc + 1 * DD + kk);
            float4 hd = *(const float4*)(hcsrc + 1 * DD + kk + 4);
            qa0 += dot8(wv, ha, hb);
            qa1 += dot8(wv, hc, hd);
        }
        s_qp[qh][0][qf] = qa0;
        s_qp[qh][1][qf] = qa1;
        __syncthreads();
        {
            int b = tid >> 8, f = tid & 255;
            s_q[b][f] = s_qp[0][b][f] + s_qp[1][b][f];
        }
        __syncthreads();

        // ---------- scores: s[t'] = sum_f w2[f]*tanh(q+ep+ab1) ----------
        // identity: w2*tanh(y) = w2 - 2*w2/(exp(2y)+1)
        float qs0[8], qs1[8];
        #pragma unroll
        for (int j = 0; j < 8; ++j) {
            qs0[j] = 2.f * (s_q[0][e0 + j] + s_ab1[e0 + j]);
            qs1[j] = 2.f * (s_q[1][e0 + j] + s_ab1[e0 + j]);
        }
        #pragma unroll
        for (int it = 0; it < 8; ++it) {           // b = 0
            int tt2 = it * 16 + rrow;
            uint4 xv = *(const uint4*)(epb0 + (size_t)tt2 * EE);
            float s = sw2;
            #pragma unroll
            for (int j = 0; j < 8; ++j) {
                unsigned int w = (&xv.x)[j >> 1];
                float xf = (j & 1) ? bfhi(w) : bflo(w);
                float e = __expf(__fmaf_rn(xf, 2.f, qs0[j]));
                s = __fmaf_rn(-tw2[j], __builtin_amdgcn_rcpf(e + 1.f), s);
            }
            #pragma unroll
            for (int off = 1; off <= 16; off <<= 1) s += __shfl_xor(s, off);
            if ((lane & 31) == 0) s_sc[tt2] = s;
        }
        #pragma unroll
        for (int it = 0; it < 8; ++it) {           // b = 1
            int tt2 = it * 16 + rrow;
            uint4 xv = *(const uint4*)(epb1 + (size_t)tt2 * EE);
            float s = sw2;
            #pragma unroll
            for (int j = 0; j < 8; ++j) {
                unsigned int w = (&xv.x)[j >> 1];
                float xf = (j & 1) ? bfhi(w) : bflo(w);
                float e = __expf(__fmaf_rn(xf, 2.f, qs1[j]));
                s = __fmaf_rn(-tw2[j], __builtin_amdgcn_rcpf(e + 1.f), s);
            }
            #pragma unroll
            for (int off = 1; off <= 16; off <<= 1) s += __shfl_xor(s, off);
            if ((lane & 31) == 0) s_sc[TT + tt2] = s;
        }
        __syncthreads();

        // ---------- softmax (wave b handles batch-row b) ----------
        if (wave < NB) {
            float v0 = s_sc[wave * TT + lane], v1 = s_sc[wave * TT + 64 + lane];
            float m = fmaxf(v0, v1);
            #pragma unroll
            for (int off = 1; off <= 32; off <<= 1) m = fmaxf(m, __shfl_xor(m, off));
            float x0 = __expf(v0 - m), x1 = __expf(v1 - m);
            float ssum = x0 + x1;
            #pragma unroll
            for (int off = 1; off <= 32; off <<= 1) ssum += __shfl_xor(ssum, off);
            float inv = 1.f / ssum;
            s_sc[wave * TT + lane] = x0 * inv;
            s_sc[wave * TT + 64 + lane] = x1 * inv;
        }
        __syncthreads();

        // ---------- ctx = attn @ ie  (fp32 stream) ----------
        float ca0[8], ca1[8];
        #pragma unroll
        for (int j = 0; j < 8; ++j) { ca0[j] = 0.f; ca1[j] = 0.f; }
        #pragma unroll
        for (int it = 0; it < 8; ++it) {           // b = 0
            int tt2 = it * 16 + rrow;
            float a = s_sc[tt2];
            const float* r = ieb0 + (size_t)tt2 * EE;
            float4 x0 = *(const float4*)r, x1 = *(const float4*)(r + 4);
            ca0[0] += a * x0.x; ca0[1] += a * x0.y; ca0[2] += a * x0.z; ca0[3] += a * x0.w;
            ca0[4] += a * x1.x; ca0[5] += a * x1.y; ca0[6] += a * x1.z; ca0[7] += a * x1.w;
        }
        #pragma unroll
        for (int it = 0; it < 8; ++it) {           // b = 1
            int tt2 = it * 16 + rrow;
            float a = s_sc[TT + tt2];
            const float* r = ieb1 + (size_t)tt2 * EE;
            float4 x0 = *(const float4*)r, x1 = *(const float4*)(r + 4);
            ca1[0] += a * x0.x; ca1[1] += a * x0.y; ca1[2] += a * x0.z; ca1[3] += a * x0.w;
            ca1[4] += a * x1.x; ca1[5] += a * x1.y; ca1[6] += a * x1.z; ca1[7] += a * x1.w;
        }
        #pragma unroll
        for (int j = 0; j < 8; ++j) {
            ca0[j] += __shfl_xor(ca0[j], 32);
            ca1[j] += __shfl_xor(ca1[j], 32);
        }
        if (lane < 32) {
            *(float4*)&s_cp[wave][0][e0]     = make_float4(ca0[0], ca0[1], ca0[2], ca0[3]);
            *(float4*)&s_cp[wave][0][e0 + 4] = make_float4(ca0[4], ca0[5], ca0[6], ca0[7]);
            *(float4*)&s_cp[wave][1][e0]     = make_float4(ca1[0], ca1[1], ca1[2], ca1[3]);
            *(float4*)&s_cp[wave][1][e0 + 4] = make_float4(ca1[4], ca1[5], ca1[6], ca1[7]);
        }
        __syncthreads();
        {
            int b = tid >> 8, e = tid & 255;
            float v = 0.f;
            #pragma unroll
            for (int w = 0; w < 8; ++w) v += s_cp[w][b][e];
            s_ctx[b][e] = v;
        }
        __syncthreads();

        // ---------- y_tilde (wave b handles row b) ----------
        if (wave < NB) {
            float p = 0.f;
            #pragma unroll
            for (int j = 0; j < 4; ++j) {
                int e = lane * 4 + j;
                p += s_ctx[wave][e] * s_fcw[e];
            }
            #pragma unroll
            for (int off = 1; off <= 32; off <<= 1) p += __shfl_xor(p, off);
            if (lane == 0)
                s_yt[wave] = p + yh[(size_t)(b0 + wave) * TT + t] * s_fcw[256] + fcb0;
        }
        __syncthreads();

        // ---------- gates = y_tilde*Wih + h@Whh.T + bias ----------
        float g00 = 0.f, g01 = 0.f, g10 = 0.f, g11 = 0.f;  // g[jsel][b]
        #pragma unroll 4
        for (int i = 0; i < 32; ++i) {
            uint4 w0 = *(const uint4*)(wP0 + (size_t)i * 8192);
            uint4 w1 = *(const uint4*)(wP1 + (size_t)i * 8192);
            int kk = i * 8;
            float4 ha = *(const float4*)&s_h[0][kk];
            float4 hb = *(const float4*)&s_h[0][kk + 4];
            float4 hc = *(const float4*)&s_h[1][kk];
            float4 hd = *(const float4*)&s_h[1][kk + 4];
            g00 += dot8(w0, ha, hb); g01 += dot8(w0, hc, hd);
            g10 += dot8(w1, ha, hb); g11 += dot8(w1, hc, hd);
        }
        {
            float yt0 = s_yt[0], yt1 = s_yt[1];
            s_g[0][tid]       = g00 + yt0 * s_wih[tid]       + s_bias[tid];
            s_g[1][tid]       = g01 + yt1 * s_wih[tid]       + s_bias[tid];
            s_g[0][tid + 512] = g10 + yt0 * s_wih[tid + 512] + s_bias[tid + 512];
            s_g[1][tid + 512] = g11 + yt1 * s_wih[tid + 512] + s_bias[tid + 512];
        }
        __syncthreads();

        // ---------- LSTM update (gate order i,f,g,o) ----------
        {
            int b = tid >> 8, d = tid & 255;
            float gi = s_g[b][d], gf = s_g[b][DD + d];
            float gg = s_g[b][2 * DD + d], go = s_g[b][3 * DD + d];
            float c2 = fsig(gf) * s_c[b][d] + fsig(gi) * ftanh(gg);
            s_c[b][d] = c2;
            s_h[b][d] = fsig(go) * ftanh(c2);
        }
        __syncthreads();
    }

    // ---------- final: out = [h, ctx] @ ffW.T + ffb ----------
    if (wave < NB) {
        float p = 0.f;
        #pragma unroll
        for (int j = 0; j < 4; ++j) {
            int e = lane * 4 + j;
            p += s_h[wave][e] * ffW[e] + s_ctx[wave][e] * ffW[EE + e];
        }
        #pragma unroll
        for (int off = 1; off <= 32; off <<= 1) p += __shfl_xor(p, off);
        if (lane == 0) out[b0 + wave] = p + ffb[0];
    }
}

extern "C" void kernel_launch(void* const* d_in, const int* in_sizes, int n_in,
                              void* d_out, int out_size, void* d_ws, size_t ws_size,
                              hipStream_t stream) {
    const float* ie  = (const float*)d_in[0];   // [B,T,E]
    const float* yh  = (const float*)d_in[1];   // [B,T,1]
    const float* aW1 = (const float*)d_in[2];   // [768,256]
    const float* ab1 = (const float*)d_in[3];   // [256]
    const float* aW2 = (const float*)d_in[4];   // [256,1]
    // d_in[5] = ab2: additive constant inside softmax -> invariant, unused
    const float* Wih = (const float*)d_in[6];   // [1024,1]
    const float* Whh = (const float*)d_in[7];   // [1024,256]
    const float* bih = (const float*)d_in[8];   // [1024]
    const float* bhh = (const float*)d_in[9];   // [1024]
    const float* fcW = (const float*)d_in[10];  // [1,257]
    const float* fcb = (const float*)d_in[11];  // [1]
    const float* ffW = (const float*)d_in[12];  // [1,512]
    const float* ffb = (const float*)d_in[13];  // [1]
    float* out = (float*)d_out;

    // workspace layout
    unsigned short* ep   = (unsigned short*)d_ws;            // B*T*E bf16 = 32 MiB
    unsigned short* aW1q = ep + (size_t)BB * TT * EE;        // 131072
    unsigned short* WhhP = aW1q + 512 * EE;                  // 262144
    float* bias = (float*)(WhhP + 262144);                   // 1024 (4B-aligned)

    k_pack<<<1540, 256, 0, stream>>>(aW1, Whh, bih, bhh, aW1q, WhhP, bias);
    k_encproj<<<2048, 256, 0, stream>>>(ie, aW1, ep);
    k_main<<<BB / NB, NTHR, 0, stream>>>(ep, ie, yh, aW1q, WhhP, bias, ab1, aW2,
                                         Wih, fcW, fcb, ffW, ffb, out);
}

// Round 3
// 2815.089 us; speedup vs baseline: 4.2798x; 2.3599x over previous
//
#include <hip/hip_runtime.h>

// DA-RNN decoder: B=512, T=128, E=256, D=256, OUT=1.
// One persistent kernel runs the whole 128-step scan: 256 blocks x 1024
// threads (16 waves/CU), NB=2 batch rows per block, h/c in LDS.
// ctx is algebraically eliminated: y_tilde and the final output only need
// dot(ctx, w) = dot(attn, ie@w), with ie@fcW / ie@ffW precomputed once.
// Weights pre-packed bf16 in load order; ep precomputed bf16.

#define BB 512
#define TT 128
#define EE 256
#define DD 256
#define NB 2
#define NTHR 1024

__device__ __forceinline__ float bflo(unsigned int u) {
    union { unsigned int i; float f; } v; v.i = u << 16; return v.f;
}
__device__ __forceinline__ float bfhi(unsigned int u) {
    union { unsigned int i; float f; } v; v.i = u & 0xFFFF0000u; return v.f;
}
__device__ __forceinline__ unsigned short f2bf(float x) {
    union { float f; unsigned int i; } v; v.f = x;
    unsigned int r = (v.i + 0x7FFFu + ((v.i >> 16) & 1u)) >> 16;
    return (unsigned short)r;
}
__device__ __forceinline__ float ftanh(float x) {
    return 1.f - 2.f * __builtin_amdgcn_rcpf(__expf(2.f * x) + 1.f);
}
__device__ __forceinline__ float fsig(float x) {
    return __builtin_amdgcn_rcpf(1.f + __expf(-x));
}
__device__ __forceinline__ float dot8(uint4 w, float4 a, float4 b) {
    return bflo(w.x) * a.x + bfhi(w.x) * a.y + bflo(w.y) * a.z + bfhi(w.y) * a.w
         + bflo(w.z) * b.x + bfhi(w.z) * b.y + bflo(w.w) * b.z + bfhi(w.w) * b.w;
}

// Pack weights to bf16 in the exact load order of k_main.
// aW1q[(g*256+f)*8+j] = aW1[g*8+j][f]      (g<64 -> k=g*8+j < 512)
// WhhP[(i*1024+jj)*8+j] = Whh[jj][i*8+j]   (i<32)
__global__ __launch_bounds__(256) void k_pack(const float* __restrict__ aW1,
                                              const float* __restrict__ Whh,
                                              const float* __restrict__ bih,
                                              const float* __restrict__ bhh,
                                              unsigned short* __restrict__ aW1q,
                                              unsigned short* __restrict__ WhhP,
                                              float* __restrict__ bias) {
    int bid = blockIdx.x, tid = threadIdx.x;
    if (bid < 512) {
        int o = bid * 256 + tid;                 // < 131072
        int g = o >> 11, f = (o >> 3) & 255, j = o & 7;
        aW1q[o] = f2bf(aW1[(g * 8 + j) * EE + f]);
    } else if (bid < 1536) {
        int o = (bid - 512) * 256 + tid;         // < 262144
        int i = o >> 13, jj = (o >> 3) & 1023, j = o & 7;
        WhhP[o] = f2bf(Whh[jj * DD + i * 8 + j]);
    } else {
        int j = (bid - 1536) * 256 + tid;        // < 1024
        bias[j] = bih[j] + bhh[j];
    }
}

// ep[n][f] = bf16( sum_e ie[n][e]*aW1[512+e][f] )
// epilogue: iefc[n] = dot(ie[n], fcW[0:256]); ieff[n] = dot(ie[n], ffW[256:512])
__global__ __launch_bounds__(256) void k_encproj(const float* __restrict__ ie,
                                                 const float* __restrict__ aW1,
                                                 const float* __restrict__ fcW,
                                                 const float* __restrict__ ffW,
                                                 unsigned short* __restrict__ ep,
                                                 float* __restrict__ iefc,
                                                 float* __restrict__ ieff) {
    __shared__ float a[32][EE];
    int row0 = blockIdx.x * 32;
    int tid = threadIdx.x;
    for (int r = 0; r < 32; ++r)
        a[r][tid] = ie[(size_t)(row0 + r) * EE + tid];
    __syncthreads();
    float acc[32];
    #pragma unroll
    for (int r = 0; r < 32; ++r) acc[r] = 0.f;
    const float* wenc = aW1 + 512 * EE;
    for (int e = 0; e < EE; e += 4) {
        float w0 = wenc[(e + 0) * EE + tid];
        float w1 = wenc[(e + 1) * EE + tid];
        float w2 = wenc[(e + 2) * EE + tid];
        float w3 = wenc[(e + 3) * EE + tid];
        #pragma unroll
        for (int r = 0; r < 32; ++r) {
            float4 av = *(const float4*)&a[r][e];
            acc[r] += av.x * w0 + av.y * w1 + av.z * w2 + av.w * w3;
        }
    }
    for (int r = 0; r < 32; ++r)
        ep[(size_t)(row0 + r) * EE + tid] = f2bf(acc[r]);

    // epilogue dots (wave w: rows w*8 .. w*8+7)
    int wave = tid >> 6, lane = tid & 63;
    float4 f1 = *(const float4*)&fcW[lane * 4];
    float4 f2 = *(const float4*)&ffW[EE + lane * 4];
    #pragma unroll
    for (int rr = 0; rr < 8; ++rr) {
        int r = wave * 8 + rr;
        float4 v = *(const float4*)&a[r][lane * 4];
        float p1 = v.x * f1.x + v.y * f1.y + v.z * f1.z + v.w * f1.w;
        float p2 = v.x * f2.x + v.y * f2.y + v.z * f2.z + v.w * f2.w;
        #pragma unroll
        for (int off = 1; off <= 32; off <<= 1) {
            p1 += __shfl_xor(p1, off);
            p2 += __shfl_xor(p2, off);
        }
        if (lane == 0) {
            iefc[row0 + r] = p1;
            ieff[row0 + r] = p2;
        }
    }
}

__global__ __launch_bounds__(NTHR) void k_main(
    const unsigned short* __restrict__ ep, const float* __restrict__ yh,
    const unsigned short* __restrict__ aW1q, const unsigned short* __restrict__ WhhP,
    const float* __restrict__ bias_, const float* __restrict__ ab1,
    const float* __restrict__ aW2, const float* __restrict__ Wih,
    const float* __restrict__ fcW, const float* __restrict__ fcb,
    const float* __restrict__ ffW, const float* __restrict__ ffb,
    const float* __restrict__ iefc, const float* __restrict__ ieff,
    float* __restrict__ out) {
    __shared__ float s_h[NB][DD];
    __shared__ float s_c[NB][DD];
    __shared__ float s_qp[2][NB][EE];     // [khalf][b][f], ab1 folded into khalf 0
    __shared__ float s_sc[NB * TT];
    __shared__ float s_g[NB][4 * DD];
    __shared__ float s_wih[4 * DD];
    __shared__ float s_bias[4 * DD];
    __shared__ float s_iefc[NB][TT];
    __shared__ float s_ieff[NB][TT];
    __shared__ float s_yh[NB][TT];
    __shared__ float s_yt[NB];
    __shared__ float s_ofs[NB];

    const int tid = threadIdx.x;
    const int wave = tid >> 6, lane = tid & 63;
    const int b0 = blockIdx.x * NB;

    for (int i = tid; i < 4 * DD; i += NTHR) { s_wih[i] = Wih[i]; s_bias[i] = bias_[i]; }
    for (int i = tid; i < NB * TT; i += NTHR) {
        int b = i >> 7, t = i & 127;
        s_iefc[b][t] = iefc[(b0 + b) * TT + t];
        s_ieff[b][t] = ieff[(b0 + b) * TT + t];
        s_yh[b][t]   = yh[(size_t)(b0 + b) * TT + t];
    }
    for (int i = tid; i < NB * DD; i += NTHR) { (&s_h[0][0])[i] = 0.f; (&s_c[0][0])[i] = 0.f; }

    // ----- q-phase mapping: thread = (b, khalf, f) -----
    const int qf = tid & 255, qkh = (tid >> 8) & 1, qb = tid >> 9;
    const float* qsrc = qkh ? s_c[qb] : s_h[qb];
    const float qinit = qkh ? 0.f : ab1[qf];
    const unsigned short* qW = aW1q + ((size_t)(qkh * 32) * 256 + qf) * 8;

    // ----- scores mapping -----
    const int e0 = (lane & 31) * 8;
    const int rsub = wave * 2 + (lane >> 5);      // [0,32)
    float tw2[8]; float sw2 = 0.f;
    #pragma unroll
    for (int j = 0; j < 8; ++j) { float w = aW2[e0 + j]; tw2[j] = 2.f * w; sw2 += w; }

    // ----- gates mapping -----
    const unsigned short* wP = WhhP + (size_t)tid * 8;

    const float fcw256 = fcW[256], fcb0 = fcb[0], ffb0 = ffb[0];

    __syncthreads();

    for (int t = 0; t < TT; ++t) {
        // ---------- q = [h;c] @ aW1[:512] (+ab1 on khalf 0) ----------
        float qa = qinit;
        #pragma unroll 8
        for (int i = 0; i < 32; ++i) {
            uint4 wv = *(const uint4*)(qW + i * 2048);
            int kk = i * 8;
            float4 a = *(const float4*)(qsrc + kk);
            float4 b = *(const float4*)(qsrc + kk + 4);
            qa += dot8(wv, a, b);
        }
        s_qp[qkh][qb][qf] = qa;
        __syncthreads();

        // ---------- scores: s[b][t'] = sum_f w2[f]*tanh(qp0+qp1+ep) ----------
        // identity: w2*tanh(y) = w2 - 2*w2/(exp(2y)+1)
        #pragma unroll
        for (int b = 0; b < NB; ++b) {
            float qs[8];
            #pragma unroll
            for (int j = 0; j < 8; ++j)
                qs[j] = 2.f * (s_qp[0][b][e0 + j] + s_qp[1][b][e0 + j]);
            const unsigned short* epb = ep + (size_t)(b0 + b) * TT * EE + e0;
            #pragma unroll
            for (int sw = 0; sw < 4; ++sw) {
                int tt2 = sw * 32 + rsub;
                uint4 xv = *(const uint4*)(epb + (size_t)tt2 * EE);
                float s = sw2;
                #pragma unroll
                for (int j = 0; j < 8; ++j) {
                    unsigned int w = (&xv.x)[j >> 1];
                    float xf = (j & 1) ? bfhi(w) : bflo(w);
                    float e = __expf(__fmaf_rn(xf, 2.f, qs[j]));
                    s = __fmaf_rn(-tw2[j], __builtin_amdgcn_rcpf(e + 1.f), s);
                }
                #pragma unroll
                for (int off = 1; off <= 16; off <<= 1) s += __shfl_xor(s, off);
                if ((lane & 31) == 0) s_sc[b * TT + tt2] = s;
            }
        }
        __syncthreads();

        // ---------- softmax + y_tilde (wave 0 -> b=0, wave 8 -> b=1) ----------
        if ((wave & 7) == 0) {
            int b = wave >> 3;
            float v0 = s_sc[b * TT + lane], v1 = s_sc[b * TT + 64 + lane];
            float m = fmaxf(v0, v1);
            #pragma unroll
            for (int off = 1; off <= 32; off <<= 1) m = fmaxf(m, __shfl_xor(m, off));
            float x0 = __expf(v0 - m), x1 = __expf(v1 - m);
            float ss = x0 + x1;
            #pragma unroll
            for (int off = 1; off <= 32; off <<= 1) ss += __shfl_xor(ss, off);
            float inv = __builtin_amdgcn_rcpf(ss);
            float a0 = x0 * inv, a1 = x1 * inv;
            float p  = a0 * s_iefc[b][lane] + a1 * s_iefc[b][64 + lane];
            float pf = (t == TT - 1) ? (a0 * s_ieff[b][lane] + a1 * s_ieff[b][64 + lane]) : 0.f;
            #pragma unroll
            for (int off = 1; off <= 32; off <<= 1) {
                p  += __shfl_xor(p, off);
                pf += __shfl_xor(pf, off);
            }
            if (lane == 0) {
                s_yt[b] = p + s_yh[b][t] * fcw256 + fcb0;
                if (t == TT - 1) s_ofs[b] = pf;
            }
        }
        __syncthreads();

        // ---------- gates: g[b][j] = h[b] . Whh[j] + yt[b]*Wih[j] + bias[j] ----------
        float g0 = 0.f, g1 = 0.f;
        #pragma unroll 8
        for (int i = 0; i < 32; ++i) {
            uint4 wv = *(const uint4*)(wP + (size_t)i * 8192);
            int kk = i * 8;
            float4 ha = *(const float4*)&s_h[0][kk];
            float4 hb = *(const float4*)&s_h[0][kk + 4];
            float4 hc = *(const float4*)&s_h[1][kk];
            float4 hd = *(const float4*)&s_h[1][kk + 4];
            g0 += dot8(wv, ha, hb);
            g1 += dot8(wv, hc, hd);
        }
        {
            float w = s_wih[tid], bv = s_bias[tid];
            s_g[0][tid] = g0 + s_yt[0] * w + bv;
            s_g[1][tid] = g1 + s_yt[1] * w + bv;
        }
        __syncthreads();

        // ---------- LSTM update (gate order i,f,g,o) ----------
        if (tid < NB * DD) {
            int b = tid >> 8, d = tid & 255;
            float gi = s_g[b][d],          gf = s_g[b][DD + d];
            float gg = s_g[b][2 * DD + d], go = s_g[b][3 * DD + d];
            float c2 = fsig(gf) * s_c[b][d] + fsig(gi) * ftanh(gg);
            s_c[b][d] = c2;
            s_h[b][d] = fsig(go) * ftanh(c2);
        }
        __syncthreads();
    }

    // ---------- final: out[b] = h.ffW[:256] + (attn127 . ieff) + ffb ----------
    if ((wave & 7) == 0) {
        int b = wave >> 3;
        float p = 0.f;
        #pragma unroll
        for (int j = 0; j < 4; ++j) {
            int d = lane * 4 + j;
            p += s_h[b][d] * ffW[d];
        }
        #pragma unroll
        for (int off = 1; off <= 32; off <<= 1) p += __shfl_xor(p, off);
        if (lane == 0) out[b0 + b] = p + s_ofs[b] + ffb0;
    }
}

extern "C" void kernel_launch(void* const* d_in, const int* in_sizes, int n_in,
                              void* d_out, int out_size, void* d_ws, size_t ws_size,
                              hipStream_t stream) {
    const float* ie  = (const float*)d_in[0];   // [B,T,E]
    const float* yh  = (const float*)d_in[1];   // [B,T,1]
    const float* aW1 = (const float*)d_in[2];   // [768,256]
    const float* ab1 = (const float*)d_in[3];   // [256]
    const float* aW2 = (const float*)d_in[4];   // [256,1]
    // d_in[5] = ab2: additive constant inside softmax -> invariant, unused
    const float* Wih = (const float*)d_in[6];   // [1024,1]
    const float* Whh = (const float*)d_in[7];   // [1024,256]
    const float* bih = (const float*)d_in[8];   // [1024]
    const float* bhh = (const float*)d_in[9];   // [1024]
    const float* fcW = (const float*)d_in[10];  // [1,257]
    const float* fcb = (const float*)d_in[11];  // [1]
    const float* ffW = (const float*)d_in[12];  // [1,512]
    const float* ffb = (const float*)d_in[13];  // [1]
    float* out = (float*)d_out;

    // workspace layout
    unsigned short* ep   = (unsigned short*)d_ws;            // 16,777,216 u16 = 32 MiB
    unsigned short* aW1q = ep + (size_t)BB * TT * EE;        // 131072 u16
    unsigned short* WhhP = aW1q + 512 * EE;                  // 262144 u16
    float* bias = (float*)(WhhP + 262144);                   // 1024 f32
    float* iefc = bias + 1024;                               // 65536 f32
    float* ieff = iefc + BB * TT;                            // 65536 f32

    k_pack<<<1540, 256, 0, stream>>>(aW1, Whh, bih, bhh, aW1q, WhhP, bias);
    k_encproj<<<2048, 256, 0, stream>>>(ie, aW1, fcW, ffW, ep, iefc, ieff);
    k_main<<<BB / NB, NTHR, 0, stream>>>(ep, yh, aW1q, WhhP, bias, ab1, aW2,
                                         Wih, fcW, fcb, ffW, ffb, iefc, ieff, out);
}

// Round 4
// 2059.978 us; speedup vs baseline: 5.8487x; 1.3666x over previous
//
#include <hip/hip_runtime.h>

// DA-RNN decoder: B=512, T=128, E=256, D=256, OUT=1.
// One persistent kernel, 256 blocks x 1024 threads (16 waves/CU), NB=2 batch
// rows per block. h/c state packed f16 in LDS (c kept fp32 in registers).
// GEMMs use v_dot2_f32_f16 (2 MAC/inst). ctx algebraically eliminated via
// precomputed ie@fcW / ie@ffW. Weights pre-packed f16 in exact load order.

#define BB 512
#define TT 128
#define EE 256
#define DD 256
#define NB 2
#define NTHR 1024

typedef _Float16 h2 __attribute__((ext_vector_type(2)));
typedef _Float16 h8 __attribute__((ext_vector_type(8)));

#if defined(__has_builtin)
#if __has_builtin(__builtin_amdgcn_fdot2)
#define HAS_FDOT2 1
#endif
#endif

#ifdef HAS_FDOT2
#define FDOT2(a, b, c) __builtin_amdgcn_fdot2(__builtin_bit_cast(h2, (a)), __builtin_bit_cast(h2, (b)), (c), false)
#else
static __device__ __forceinline__ float FDOT2(unsigned int a, unsigned int b, float c) {
    h2 x = __builtin_bit_cast(h2, a), y = __builtin_bit_cast(h2, b);
    return c + (float)x[0] * (float)y[0] + (float)x[1] * (float)y[1];
}
#endif

static __device__ __forceinline__ float dot8u4(uint4 w, uint4 h, float acc) {
    acc = FDOT2(w.x, h.x, acc);
    acc = FDOT2(w.y, h.y, acc);
    acc = FDOT2(w.z, h.z, acc);
    acc = FDOT2(w.w, h.w, acc);
    return acc;
}
static __device__ __forceinline__ unsigned int pkh(float a, float b) {
    union { _Float16 h; unsigned short s; } ua, ub;
    ua.h = (_Float16)a; ub.h = (_Float16)b;
    return (unsigned int)ua.s | ((unsigned int)ub.s << 16);
}
__device__ __forceinline__ float ftanh(float x) {
    return 1.f - 2.f * __builtin_amdgcn_rcpf(__expf(2.f * x) + 1.f);
}
__device__ __forceinline__ float fsig(float x) {
    return __builtin_amdgcn_rcpf(1.f + __expf(-x));
}

// Pack weights to f16 in the exact load order of k_main.
// aW1h[(g*256+f)*8+j] = aW1[g*8+j][f]      (g<64 -> k=g*8+j < 512)
// WhhH[(i*1024+jj)*8+m] = Whh[jj][i*8+m]   (i<32)
__global__ __launch_bounds__(256) void k_pack(const float* __restrict__ aW1,
                                              const float* __restrict__ Whh,
                                              const float* __restrict__ bih,
                                              const float* __restrict__ bhh,
                                              _Float16* __restrict__ aW1h,
                                              _Float16* __restrict__ WhhH,
                                              float* __restrict__ bias) {
    int bid = blockIdx.x, tid = threadIdx.x;
    if (bid < 512) {
        int o = bid * 256 + tid;                 // < 131072
        int g = o >> 11, f = (o >> 3) & 255, j = o & 7;
        aW1h[o] = (_Float16)aW1[(g * 8 + j) * EE + f];
    } else if (bid < 1536) {
        int o = (bid - 512) * 256 + tid;         // < 262144
        int i = o >> 13, jj = (o >> 3) & 1023, m = o & 7;
        WhhH[o] = (_Float16)Whh[jj * DD + i * 8 + m];
    } else {
        int j = (bid - 1536) * 256 + tid;        // < 1024
        bias[j] = bih[j] + bhh[j];
    }
}

// ep[n][f] = f16( sum_e ie[n][e]*aW1[512+e][f] )
// epilogue: iefc[n] = dot(ie[n], fcW[0:256]); ieff[n] = dot(ie[n], ffW[256:512])
__global__ __launch_bounds__(256) void k_encproj(const float* __restrict__ ie,
                                                 const float* __restrict__ aW1,
                                                 const float* __restrict__ fcW,
                                                 const float* __restrict__ ffW,
                                                 _Float16* __restrict__ ep,
                                                 float* __restrict__ iefc,
                                                 float* __restrict__ ieff) {
    __shared__ float a[32][EE];
    int row0 = blockIdx.x * 32;
    int tid = threadIdx.x;
    for (int r = 0; r < 32; ++r)
        a[r][tid] = ie[(size_t)(row0 + r) * EE + tid];
    __syncthreads();
    float acc[32];
    #pragma unroll
    for (int r = 0; r < 32; ++r) acc[r] = 0.f;
    const float* wenc = aW1 + 512 * EE;
    for (int e = 0; e < EE; e += 4) {
        float w0 = wenc[(e + 0) * EE + tid];
        float w1 = wenc[(e + 1) * EE + tid];
        float w2 = wenc[(e + 2) * EE + tid];
        float w3 = wenc[(e + 3) * EE + tid];
        #pragma unroll
        for (int r = 0; r < 32; ++r) {
            float4 av = *(const float4*)&a[r][e];
            acc[r] += av.x * w0 + av.y * w1 + av.z * w2 + av.w * w3;
        }
    }
    for (int r = 0; r < 32; ++r)
        ep[(size_t)(row0 + r) * EE + tid] = (_Float16)acc[r];

    // epilogue dots (wave w: rows w*8 .. w*8+7)
    int wave = tid >> 6, lane = tid & 63;
    float4 f1 = *(const float4*)&fcW[lane * 4];
    float4 f2 = *(const float4*)&ffW[EE + lane * 4];
    #pragma unroll
    for (int rr = 0; rr < 8; ++rr) {
        int r = wave * 8 + rr;
        float4 v = *(const float4*)&a[r][lane * 4];
        float p1 = v.x * f1.x + v.y * f1.y + v.z * f1.z + v.w * f1.w;
        float p2 = v.x * f2.x + v.y * f2.y + v.z * f2.z + v.w * f2.w;
        #pragma unroll
        for (int off = 1; off <= 32; off <<= 1) {
            p1 += __shfl_xor(p1, off);
            p2 += __shfl_xor(p2, off);
        }
        if (lane == 0) {
            iefc[row0 + r] = p1;
            ieff[row0 + r] = p2;
        }
    }
}

__global__ __launch_bounds__(NTHR) void k_main(
    const _Float16* __restrict__ ep, const float* __restrict__ yh,
    const _Float16* __restrict__ aW1h, const _Float16* __restrict__ WhhH,
    const float* __restrict__ bias_, const float* __restrict__ ab1,
    const float* __restrict__ aW2, const float* __restrict__ Wih,
    const float* __restrict__ fcW, const float* __restrict__ fcb,
    const float* __restrict__ ffW, const float* __restrict__ ffb,
    const float* __restrict__ iefc, const float* __restrict__ ieff,
    float* __restrict__ out) {
    __shared__ unsigned int s_hc16[NB][2][128];  // [b][0=h,1=c], f16 pairs
    __shared__ float s_qp[2][NB][EE];            // transposed: [kh][b][32*j + (f>>3)]
    __shared__ float s_sc[NB * TT];
    __shared__ float s_g[NB][4 * DD];            // raw h.Whh + bias
    __shared__ float s_wih[4 * DD];
    __shared__ float s_iefc[NB][TT];
    __shared__ float s_ieff[NB][TT];
    __shared__ float s_yh[NB][TT];
    __shared__ float s_yt[NB];
    __shared__ float s_ofs[NB];

    const int tid = threadIdx.x;
    const int wave = tid >> 6, lane = tid & 63;
    const int b0 = blockIdx.x * NB;

    for (int i = tid; i < 4 * DD; i += NTHR) s_wih[i] = Wih[i];
    for (int i = tid; i < NB * TT; i += NTHR) {
        int b = i >> 7, t = i & 127;
        s_iefc[b][t] = iefc[(b0 + b) * TT + t];
        s_ieff[b][t] = ieff[(b0 + b) * TT + t];
        s_yh[b][t]   = yh[(size_t)(b0 + b) * TT + t];
    }
    for (int i = tid; i < NB * 2 * 128; i += NTHR) (&s_hc16[0][0][0])[i] = 0u;

    // ----- q mapping: thread = (qb, qkh, qf) -----
    const int qf = tid & 255, qkh = (tid >> 8) & 1, qb = tid >> 9;
    const float qinit = qkh ? 0.f : ab1[qf];
    const uint4* qW = (const uint4*)aW1h + ((size_t)(qkh * 32) * 256 + qf);
    const int qperm = 32 * 0 + (qf >> 3) + 32 * (qf & 7) - 0;  // 32*(f&7) + (f>>3)

    // ----- gates mapping: thread = gate row j -----
    const uint4* wP = (const uint4*)WhhH + tid;
    const float biasv = bias_[tid];

    // ----- scores mapping -----
    const int l5 = lane & 31;
    const int rsub = wave * 2 + (lane >> 5);     // [0,32)
    const int e0 = l5 * 8;
    float tw2[8]; float sw2 = 0.f;
    #pragma unroll
    for (int j = 0; j < 8; ++j) { float w = aW2[e0 + j]; tw2[j] = 2.f * w; sw2 += w; }

    const float fcw256 = fcW[256], fcb0 = fcb[0], ffb0 = ffb[0];
    float c_reg = 0.f;                           // fp32 cell state (tid<512)

    __syncthreads();

    for (int t = 0; t < TT; ++t) {
        // ---------- A: q = [h;c]@aW1 (+ab1)  AND  g = h@Whh.T + bias ----------
        float qa = qinit;
        float g0 = biasv, g1 = biasv;
        #pragma unroll 8
        for (int i = 0; i < 32; ++i) {
            uint4 wv = qW[(size_t)i * 256];
            uint4 hv = *(const uint4*)&s_hc16[qb][qkh][i * 4];
            qa = dot8u4(wv, hv, qa);
            uint4 gw = wP[(size_t)i * 1024];
            uint4 h0 = *(const uint4*)&s_hc16[0][0][i * 4];
            uint4 h1 = *(const uint4*)&s_hc16[1][0][i * 4];
            g0 = dot8u4(gw, h0, g0);
            g1 = dot8u4(gw, h1, g1);
        }
        s_qp[qkh][qb][qperm] = qa;
        s_g[0][tid] = g0;
        s_g[1][tid] = g1;
        __syncthreads();

        // ---------- B: scores s[b][t'] = sum_f w2[f]*tanh(qp0+qp1+ep) ----------
        #pragma unroll
        for (int b = 0; b < NB; ++b) {
            float qs[8];
            #pragma unroll
            for (int j = 0; j < 8; ++j)
                qs[j] = 2.f * (s_qp[0][b][l5 + 32 * j] + s_qp[1][b][l5 + 32 * j]);
            const _Float16* eph = ep + (size_t)(b0 + b) * TT * EE + e0;
            #pragma unroll
            for (int sw = 0; sw < 4; ++sw) {
                int tt2 = sw * 32 + rsub;
                h8 xv = *(const h8*)(eph + (size_t)tt2 * EE);
                float s = sw2;
                #pragma unroll
                for (int j = 0; j < 8; ++j) {
                    float e = __expf(__fmaf_rn((float)xv[j], 2.f, qs[j]));
                    s = __fmaf_rn(-tw2[j], __builtin_amdgcn_rcpf(e + 1.f), s);
                }
                #pragma unroll
                for (int off = 1; off <= 16; off <<= 1) s += __shfl_xor(s, off);
                if (l5 == 0) s_sc[b * TT + tt2] = s;
            }
        }
        __syncthreads();

        // ---------- C: softmax + y_tilde (wave 0 -> b=0, wave 8 -> b=1) ----------
        if ((wave & 7) == 0) {
            int b = wave >> 3;
            float v0 = s_sc[b * TT + lane], v1 = s_sc[b * TT + 64 + lane];
            float m = fmaxf(v0, v1);
            #pragma unroll
            for (int off = 1; off <= 32; off <<= 1) m = fmaxf(m, __shfl_xor(m, off));
            float x0 = __expf(v0 - m), x1 = __expf(v1 - m);
            float ss = x0 + x1;
            #pragma unroll
            for (int off = 1; off <= 32; off <<= 1) ss += __shfl_xor(ss, off);
            float inv = __builtin_amdgcn_rcpf(ss);
            float a0 = x0 * inv, a1 = x1 * inv;
            float p  = a0 * s_iefc[b][lane] + a1 * s_iefc[b][64 + lane];
            float pf = (t == TT - 1) ? (a0 * s_ieff[b][lane] + a1 * s_ieff[b][64 + lane]) : 0.f;
            #pragma unroll
            for (int off = 1; off <= 32; off <<= 1) {
                p  += __shfl_xor(p, off);
                pf += __shfl_xor(pf, off);
            }
            if (lane == 0) {
                s_yt[b] = p + s_yh[b][t] * fcw256 + fcb0;
                if (t == TT - 1) s_ofs[b] = pf;
            }
        }
        __syncthreads();

        // ---------- D: apply yt + LSTM update (tid<512), pack h/c to f16 ----------
        if (tid < NB * DD) {
            int b = tid >> 8, d = tid & 255;
            float yt = s_yt[b];
            float gi = s_g[b][d]          + yt * s_wih[d];
            float gf = s_g[b][DD + d]     + yt * s_wih[DD + d];
            float gg = s_g[b][2 * DD + d] + yt * s_wih[2 * DD + d];
            float go = s_g[b][3 * DD + d] + yt * s_wih[3 * DD + d];
            float c2 = fsig(gf) * c_reg + fsig(gi) * ftanh(gg);
            c_reg = c2;
            float hn = fsig(go) * ftanh(c2);
            float hO = __shfl_xor(hn, 1);
            float cO = __shfl_xor(c2, 1);
            if (!(d & 1)) {
                s_hc16[b][0][d >> 1] = pkh(hn, hO);
                s_hc16[b][1][d >> 1] = pkh(c2, cO);
            }
        }
        __syncthreads();
    }

    // ---------- final: out[b] = h.ffW[:256] + (attn_last . ieff) + ffb ----------
    if ((wave & 7) == 0) {
        int b = wave >> 3;
        unsigned int p0 = s_hc16[b][0][lane * 2];
        unsigned int p1 = s_hc16[b][0][lane * 2 + 1];
        h2 ha = __builtin_bit_cast(h2, p0), hb = __builtin_bit_cast(h2, p1);
        float4 w = *(const float4*)&ffW[lane * 4];
        float p = (float)ha[0] * w.x + (float)ha[1] * w.y
                + (float)hb[0] * w.z + (float)hb[1] * w.w;
        #pragma unroll
        for (int off = 1; off <= 32; off <<= 1) p += __shfl_xor(p, off);
        if (lane == 0) out[b0 + b] = p + s_ofs[b] + ffb0;
    }
}

extern "C" void kernel_launch(void* const* d_in, const int* in_sizes, int n_in,
                              void* d_out, int out_size, void* d_ws, size_t ws_size,
                              hipStream_t stream) {
    const float* ie  = (const float*)d_in[0];   // [B,T,E]
    const float* yh  = (const float*)d_in[1];   // [B,T,1]
    const float* aW1 = (const float*)d_in[2];   // [768,256]
    const float* ab1 = (const float*)d_in[3];   // [256]
    const float* aW2 = (const float*)d_in[4];   // [256,1]
    // d_in[5] = ab2: additive constant inside softmax -> invariant, unused
    const float* Wih = (const float*)d_in[6];   // [1024,1]
    const float* Whh = (const float*)d_in[7];   // [1024,256]
    const float* bih = (const float*)d_in[8];   // [1024]
    const float* bhh = (const float*)d_in[9];   // [1024]
    const float* fcW = (const float*)d_in[10];  // [1,257]
    const float* fcb = (const float*)d_in[11];  // [1]
    const float* ffW = (const float*)d_in[12];  // [1,512]
    const float* ffb = (const float*)d_in[13];  // [1]
    float* out = (float*)d_out;

    // workspace layout
    _Float16* ep   = (_Float16*)d_ws;                        // 16,777,216 f16 = 32 MiB
    _Float16* aW1h = ep + (size_t)BB * TT * EE;              // 131072 f16
    _Float16* WhhH = aW1h + 512 * EE;                        // 262144 f16
    float* bias = (float*)(WhhH + 262144);                   // 1024 f32
    float* iefc = bias + 1024;                               // 65536 f32
    float* ieff = iefc + BB * TT;                            // 65536 f32

    k_pack<<<1540, 256, 0, stream>>>(aW1, Whh, bih, bhh, aW1h, WhhH, bias);
    k_encproj<<<2048, 256, 0, stream>>>(ie, aW1, fcW, ffW, ep, iefc, ieff);
    k_main<<<BB / NB, NTHR, 0, stream>>>(ep, yh, aW1h, WhhH, bias, ab1, aW2,
                                         Wih, fcW, fcb, ffW, ffb, iefc, ieff, out);
}